// Round 21
// baseline (102.178 us; speedup 1.0000x reference)
//
#include <hip/hip_runtime.h>
#include <hip/hip_fp16.h>
#include <math.h>
#include <stdint.h>

#define D 128
#define MAXDEG 32
typedef __attribute__((ext_vector_type(8))) _Float16 f16x8;
typedef __attribute__((ext_vector_type(4))) float f32x4;
typedef unsigned short ushort_t;

__device__ inline unsigned pack_f16(float a, float b) {
    __half2 h = __floats2half2_rn(a, b);
    return __builtin_bit_cast(unsigned, h);
}
__device__ inline ushort_t f16_of(float f) {
    __half h = __float2half_rn(f);
    return __builtin_bit_cast(ushort_t, h);
}
__device__ inline __half2 hmax2(__half2 a, __half2 b) {
    unsigned ua = __builtin_bit_cast(unsigned, a);
    unsigned ub = __builtin_bit_cast(unsigned, b);
    unsigned r;
    asm("v_pk_max_f16 %0, %1, %2" : "=v"(r) : "v"(ua), "v"(ub));
    return __builtin_bit_cast(__half2, r);
}

struct __align__(16) H8 { __half2 h[4]; };

// ---- prep: weight transpose (blocks 0..3) + zero count / ov_cnt ----
__global__ void prep(const float* __restrict__ W0, const float* __restrict__ W1,
                     const float* __restrict__ W2, const float* __restrict__ W3,
                     ushort_t* __restrict__ Wt4, int* __restrict__ count,
                     int* __restrict__ ov_cnt, int N) {
    __shared__ ushort_t sT[D * D];
    const int t = threadIdx.x;
    if (blockIdx.x < 4) {
        const float* src = blockIdx.x == 0 ? W0 : blockIdx.x == 1 ? W1 : blockIdx.x == 2 ? W2 : W3;
        ushort_t* dst = Wt4 + (size_t)blockIdx.x * (D * D);
        for (int i = t; i < D * D; i += 256) {
            const int k = i >> 7, col = i & 127;
            sT[col * D + k] = f16_of(src[i]);
        }
        __syncthreads();
        const uint4* s8 = (const uint4*)sT;
        uint4* d8 = (uint4*)dst;
        for (int i = t; i < D * D / 8; i += 256) d8[i] = s8[i];
    } else {
        if (blockIdx.x == 4 && t == 0) *ov_cnt = 0;
        for (int i = (blockIdx.x - 4) * 256 + t; i < N; i += (gridDim.x - 4) * 256)
            count[i] = 0;
    }
}

// ---- LDS staging helpers (XOR-swizzled layout, 256B rows) ----
__device__ inline void stage_w(ushort_t* sW, const ushort_t* Wt, int t) {
    const uint4* src = (const uint4*)Wt;
    for (int s = t; s < 2048; s += 256) {
        const int col = s >> 4;
        const int off = (s & 15) * 16;
        *(uint4*)((char*)sW + col * 256 + (off ^ ((col & 7) << 4))) = src[s];
    }
}
__device__ inline void stage_x(ushort_t* sX, const float* X, const int* rowidx,
                               int r0, int M, int t) {
    const int row = t >> 2, q = t & 3;
    const int gr = r0 + row;
    if (gr < M) {
        const int src = rowidx ? rowidx[gr] : gr;
        const float* xp = X + (size_t)src * D + q * 32;
        #pragma unroll
        for (int s = 0; s < 4; ++s) {
            const float4 v0 = *(const float4*)(xp + s * 8);
            const float4 v1 = *(const float4*)(xp + s * 8 + 4);
            uint4 pk;
            pk.x = pack_f16(v0.x, v0.y); pk.y = pack_f16(v0.z, v0.w);
            pk.z = pack_f16(v1.x, v1.y); pk.w = pack_f16(v1.z, v1.w);
            const int off = q * 64 + s * 16;
            *(uint4*)((char*)sX + row * 256 + (off ^ ((row & 7) << 4))) = pk;
        }
    }
}

// dual-weight 64-row tile: Y[gr][0:128]=X@(sWA), Y[gr][128:256]=X@(sWB), fp16 out
__device__ inline void dual_tile(const float* X, int r0, int M, ushort_t* Y,
                                 ushort_t* sWA, ushort_t* sWB, ushort_t* sX, int t) {
    const int wave = t >> 6, lane = t & 63;
    const int l15 = lane & 15, lg = lane >> 4;
    stage_x(sX, X, nullptr, r0, M, t);
    __syncthreads();
    f32x4 accA[8], accB[8];
    #pragma unroll
    for (int ct = 0; ct < 8; ++ct) {
        accA[ct] = (f32x4){0.f, 0.f, 0.f, 0.f};
        accB[ct] = (f32x4){0.f, 0.f, 0.f, 0.f};
    }
    #pragma unroll
    for (int kc = 0; kc < 4; ++kc) {
        const int koff = kc * 64 + lg * 16;
        const int arow = wave * 16 + l15;
        const f16x8 afrag = *(const f16x8*)((char*)sX + arow * 256 + (koff ^ ((arow & 7) << 4)));
        #pragma unroll
        for (int ct = 0; ct < 8; ++ct) {
            const int col = ct * 16 + l15;
            const int sw = koff ^ ((col & 7) << 4);
            const f16x8 bfA = *(const f16x8*)((char*)sWA + col * 256 + sw);
            const f16x8 bfB = *(const f16x8*)((char*)sWB + col * 256 + sw);
            accA[ct] = __builtin_amdgcn_mfma_f32_16x16x32_f16(afrag, bfA, accA[ct], 0, 0, 0);
            accB[ct] = __builtin_amdgcn_mfma_f32_16x16x32_f16(afrag, bfB, accB[ct], 0, 0, 0);
        }
    }
    __syncthreads();   // all LDS reads done before caller restages
    #pragma unroll
    for (int q2 = 0; q2 < 4; ++q2) {
        const int gr2 = r0 + wave * 16 + lg * 4 + q2;
        if (gr2 < M) {
            #pragma unroll
            for (int ct = 0; ct < 8; ++ct) {
                const int col = ct * 16 + l15;
                Y[(size_t)gr2 * 256 + col]       = f16_of(accA[ct][q2]);
                Y[(size_t)gr2 * 256 + 128 + col] = f16_of(accB[ct][q2]);
            }
        }
    }
}

// ---------- fused: GEMM role first, then every block scatters a static edge slice ------
// blocks [0,HBLK):          combo = [hidden@Wh | hidden@Ws], grid-stride tiles
// blocks [HBLK,HBLK+RB):    hrcombo = [rela@Wh | rela@Wr]
// block  HBLK+RB:           qrb = rela[q_rel]@Wqr + bias
// then ALL blocks:          scatter edges [bid*per, (bid+1)*per)
__global__ __launch_bounds__(256, 2)
void scatter_gemm4(const int* __restrict__ edges, int* __restrict__ count,
                   unsigned* __restrict__ bucket, uint2* __restrict__ ov,
                   int* __restrict__ ov_cnt, int E,
                   const float* __restrict__ hidden, const float* __restrict__ rela,
                   const ushort_t* __restrict__ Wt4, const float* __restrict__ bias,
                   const int* __restrict__ q_rel,
                   ushort_t* __restrict__ combo, ushort_t* __restrict__ hrcombo,
                   ushort_t* __restrict__ qrb, int N, int R, int B,
                   int HBLK, int TB, int RB) {
    __shared__ ushort_t sWA[D * D];  // 32 KB
    __shared__ ushort_t sWB[D * D];  // 32 KB
    __shared__ ushort_t sX[64 * D];  // 16 KB  (exactly 80 KB -> 2 blocks/CU)
    const int t = threadIdx.x;
    const int bid = blockIdx.x, nb = gridDim.x;
    const int wave = t >> 6, lane = t & 63;
    const int l15 = lane & 15, lg = lane >> 4;

    // ---- phase A: GEMM role ----
    if (bid < HBLK) {              // combo = [hidden@Wh | hidden@Ws]
        stage_w(sWA, Wt4 + 3 * D * D, t);       // Wh^T
        stage_w(sWB, Wt4, t);                   // Ws^T
        __syncthreads();
        for (int tile = bid; tile < TB; tile += HBLK)
            dual_tile(hidden, tile * 64, N, combo, sWA, sWB, sX, t);
    } else if (bid < HBLK + RB) {  // hrcombo = [rela@Wh | rela@Wr]
        stage_w(sWA, Wt4 + 3 * D * D, t);       // Wh^T
        stage_w(sWB, Wt4 + D * D, t);           // Wr^T
        __syncthreads();
        dual_tile(rela, (bid - HBLK) * 64, R, hrcombo, sWA, sWB, sX, t);
    } else {                       // qrb = rela[q_rel]@Wqr + bias
        stage_w(sWA, Wt4 + 2 * D * D, t);       // Wqr^T
        __syncthreads();
        stage_x(sX, rela, q_rel, 0, B, t);
        __syncthreads();
        f32x4 acc[8];
        #pragma unroll
        for (int ct = 0; ct < 8; ++ct) acc[ct] = (f32x4){0.f, 0.f, 0.f, 0.f};
        #pragma unroll
        for (int kc = 0; kc < 4; ++kc) {
            const int koff = kc * 64 + lg * 16;
            const int arow = wave * 16 + l15;
            const f16x8 afrag = *(const f16x8*)((char*)sX + arow * 256 + (koff ^ ((arow & 7) << 4)));
            #pragma unroll
            for (int ct = 0; ct < 8; ++ct) {
                const int col = ct * 16 + l15;
                const f16x8 bf = *(const f16x8*)((char*)sWA + col * 256 + (koff ^ ((col & 7) << 4)));
                acc[ct] = __builtin_amdgcn_mfma_f32_16x16x32_f16(afrag, bf, acc[ct], 0, 0, 0);
            }
        }
        #pragma unroll
        for (int q2 = 0; q2 < 4; ++q2) {
            const int gr2 = wave * 16 + lg * 4 + q2;
            if (gr2 < B) {
                #pragma unroll
                for (int ct = 0; ct < 8; ++ct) {
                    const int col = ct * 16 + l15;
                    qrb[(size_t)gr2 * 128 + col] = f16_of(acc[ct][q2] + bias[col]);
                }
            }
        }
    }

    // ---- phase B: static edge slice scatter (independent of phase A output) ----
    {
        const int per = (E + nb - 1) / nb;
        const int s0 = bid * per;
        const int s1 = (s0 + per < E) ? s0 + per : E;
        const uint2* e2 = (const uint2*)edges;
        for (int e = s0 + t; e < s1; e += 256) {
            const unsigned r_idx = e2[e * 3 + 0].x;
            const unsigned rel   = e2[e * 3 + 1].x;
            const uint2 so       = e2[e * 3 + 2];     // .x=sub .y=obj
            const unsigned rc = so.x | (rel << 16) | (r_idx << 25);
            const int pos = atomicAdd(&count[so.y], 1);
            if (pos < MAXDEG) bucket[(size_t)so.y * MAXDEG + pos] = rc;
            else { const int i = atomicAdd(ov_cnt, 1); ov[i] = make_uint2(so.y, rc); }
        }
    }
}

// ------- per-node aggregation (static node map, fp16): out = relu(sum a*(hw+rw)) -------
__global__ void agg_v11(const unsigned* __restrict__ bucket, const int* __restrict__ count,
                        const uint2* __restrict__ ov, const int* __restrict__ ov_cnt,
                        const __half* __restrict__ combo,    // [N][256]: hw | hs_proj
                        const __half* __restrict__ hrcombo,  // [R][256]: rw | hr_proj
                        const __half* __restrict__ qrb,      // [B][128]: qr_proj
                        const float* __restrict__ Wa,
                        float* __restrict__ out, int N) {
    const int gtid = blockIdx.x * blockDim.x + threadIdx.x;
    const int wave = gtid >> 6;
    const int lane = threadIdx.x & 63;
    const int nwaves = (gridDim.x * blockDim.x) >> 6;
    const int grp = lane >> 4;        // 0..3 : edge slot within wave
    const int sl  = lane & 15;        // 0..15
    const int c   = sl * 8;           // 8 cols per lane
    __half2 wah[4];
    {
        const float4 w0 = *(const float4*)(Wa + c);
        const float4 w1 = *(const float4*)(Wa + c + 4);
        wah[0] = __floats2half2_rn(w0.x, w0.y);
        wah[1] = __floats2half2_rn(w0.z, w0.w);
        wah[2] = __floats2half2_rn(w1.x, w1.y);
        wah[3] = __floats2half2_rn(w1.z, w1.w);
    }
    const __half2 zero2 = __floats2half2_rn(0.f, 0.f);
    for (int n = wave; n < N; n += nwaves) {
        const int deg = count[n];
        const int lim = deg < MAXDEG ? deg : MAXDEG;
        __half2 a0 = zero2, a1 = zero2, a2 = zero2, a3 = zero2;
        for (int e = grp; e < lim; e += 4) {
            const unsigned rc = bucket[(size_t)n * MAXDEG + e];
            const int sub  = rc & 0xFFFF;
            const int rel  = (rc >> 16) & 0x1FF;
            const int ridx = rc >> 25;
            const H8 uhw  = *(const H8*)(combo + (size_t)sub * 256 + c);
            const H8 uhsp = *(const H8*)(combo + (size_t)sub * 256 + 128 + c);
            const H8 urw  = *(const H8*)(hrcombo + (size_t)rel * 256 + c);
            const H8 uhrp = *(const H8*)(hrcombo + (size_t)rel * 256 + 128 + c);
            const H8 uqrp = *(const H8*)(qrb + (size_t)ridx * 128 + c);
            __half2 d2 = zero2;
            #pragma unroll
            for (int j = 0; j < 4; ++j) {
                const __half2 p = hmax2(__hadd2(__hadd2(uhsp.h[j], uhrp.h[j]), uqrp.h[j]), zero2);
                d2 = __hfma2(p, wah[j], d2);
            }
            float part = __low2float(d2) + __high2float(d2);
            #pragma unroll
            for (int off = 8; off > 0; off >>= 1) part += __shfl_xor(part, off, 64);
            const float alpha = 1.f / (1.f + __expf(-part));
            const __half2 al2 = __float2half2_rn(alpha);
            a0 = __hfma2(__hadd2(uhw.h[0], urw.h[0]), al2, a0);
            a1 = __hfma2(__hadd2(uhw.h[1], urw.h[1]), al2, a1);
            a2 = __hfma2(__hadd2(uhw.h[2], urw.h[2]), al2, a2);
            a3 = __hfma2(__hadd2(uhw.h[3], urw.h[3]), al2, a3);
        }
        if (deg > MAXDEG) {   // exact-correctness overflow path (empty in practice)
            const int ovn = *ov_cnt;
            for (int i = grp; i < ovn; i += 4) {
                const uint2 o = ov[i];
                if ((int)o.x != n) continue;
                const unsigned rc = o.y;
                const int sub  = rc & 0xFFFF;
                const int rel  = (rc >> 16) & 0x1FF;
                const int ridx = rc >> 25;
                const H8 uhw  = *(const H8*)(combo + (size_t)sub * 256 + c);
                const H8 uhsp = *(const H8*)(combo + (size_t)sub * 256 + 128 + c);
                const H8 urw  = *(const H8*)(hrcombo + (size_t)rel * 256 + c);
                const H8 uhrp = *(const H8*)(hrcombo + (size_t)rel * 256 + 128 + c);
                const H8 uqrp = *(const H8*)(qrb + (size_t)ridx * 128 + c);
                __half2 d2 = zero2;
                #pragma unroll
                for (int j = 0; j < 4; ++j) {
                    const __half2 p = hmax2(__hadd2(__hadd2(uhsp.h[j], uhrp.h[j]), uqrp.h[j]), zero2);
                    d2 = __hfma2(p, wah[j], d2);
                }
                float part = __low2float(d2) + __high2float(d2);
                #pragma unroll
                for (int off = 8; off > 0; off >>= 1) part += __shfl_xor(part, off, 64);
                const float alpha = 1.f / (1.f + __expf(-part));
                const __half2 al2 = __float2half2_rn(alpha);
                a0 = __hfma2(__hadd2(uhw.h[0], urw.h[0]), al2, a0);
                a1 = __hfma2(__hadd2(uhw.h[1], urw.h[1]), al2, a1);
                a2 = __hfma2(__hadd2(uhw.h[2], urw.h[2]), al2, a2);
                a3 = __hfma2(__hadd2(uhw.h[3], urw.h[3]), al2, a3);
            }
        }
        __half2 aa[4] = {a0, a1, a2, a3};
        #pragma unroll
        for (int j = 0; j < 4; ++j) {   // combine the 4 edge slots
            unsigned u = __builtin_bit_cast(unsigned, aa[j]);
            __half2 s = __hadd2(aa[j], __builtin_bit_cast(__half2, __shfl_xor(u, 16, 64)));
            u = __builtin_bit_cast(unsigned, s);
            aa[j] = __hadd2(s, __builtin_bit_cast(__half2, __shfl_xor(u, 32, 64)));
        }
        if (grp == 0) {
            const float4 o0 = make_float4(fmaxf(__low2float(aa[0]), 0.f), fmaxf(__high2float(aa[0]), 0.f),
                                          fmaxf(__low2float(aa[1]), 0.f), fmaxf(__high2float(aa[1]), 0.f));
            const float4 o1 = make_float4(fmaxf(__low2float(aa[2]), 0.f), fmaxf(__high2float(aa[2]), 0.f),
                                          fmaxf(__low2float(aa[3]), 0.f), fmaxf(__high2float(aa[3]), 0.f));
            *(float4*)(out + (size_t)n * D + c)     = o0;
            *(float4*)(out + (size_t)n * D + c + 4) = o1;
        }
    }
}

extern "C" void kernel_launch(void* const* d_in, const int* in_sizes, int n_in,
                              void* d_out, int out_size, void* d_ws, size_t ws_size,
                              hipStream_t stream) {
    const int*   q_rel  = (const int*)d_in[0];
    const float* hidden = (const float*)d_in[1];
    const int*   edges  = (const int*)d_in[2];
    const float* rela   = (const float*)d_in[3];
    const float* Ws     = (const float*)d_in[4];
    const float* Wr     = (const float*)d_in[5];
    const float* Wqr_w  = (const float*)d_in[6];
    const float* Wqr_b  = (const float*)d_in[7];
    const float* Wa     = (const float*)d_in[8];
    const float* Wh     = (const float*)d_in[9];

    const int B = in_sizes[0];
    const int N = in_sizes[1] / D;
    const int E = in_sizes[2] / 6;
    const int R = in_sizes[3] / D;

    ushort_t* combo   = (ushort_t*)d_ws;                 // N*256 fp16: hw | hs_proj
    ushort_t* hrcombo = combo + (size_t)N * 256;         // R*256 fp16: rw | hr_proj
    ushort_t* qrb     = hrcombo + (size_t)R * 256;       // B*128 fp16
    ushort_t* Wt4     = qrb + (size_t)B * 128;           // 4*128*128 fp16
    int* count  = (int*)(Wt4 + 4 * D * D);               // N
    int* ov_cnt = count + N;                             // 1 (+pad)
    unsigned* bucket = (unsigned*)(ov_cnt + 4);          // N*MAXDEG
    uint2* ov = (uint2*)(((uintptr_t)(bucket + (size_t)N * MAXDEG) + 15) & ~(uintptr_t)15); // E

    // 1) weight transpose + zero counters
    prep<<<200, 256, 0, stream>>>(Ws, Wr, Wqr_w, Wh, Wt4, count, ov_cnt, N);

    // 2) GEMM role on all blocks, then per-block static scatter slices (grid = 512)
    const int TB = (N + 63) / 64;
    const int RB = (R + 63) / 64;
    const int GRID = 512;
    const int HBLK = GRID - RB - 1;
    scatter_gemm4<<<GRID, 256, 0, stream>>>(
        edges, count, bucket, ov, ov_cnt, E, hidden, rela, Wt4, Wqr_b, q_rel,
        combo, hrcombo, qrb, N, R, B, HBLK, TB, RB);

    // 3) gather-aggregate + relu -> d_out (static node map)
    agg_v11<<<2048, 256, 0, stream>>>(bucket, count, ov, ov_cnt,
                                      (const __half*)combo, (const __half*)hrcombo,
                                      (const __half*)qrb, Wa, (float*)d_out, N);
}

// Round 22
// 89.111 us; speedup vs baseline: 1.1466x; 1.1466x over previous
//
#include <hip/hip_runtime.h>
#include <hip/hip_fp16.h>
#include <math.h>
#include <stdint.h>

#define D 128
#define MAXDEG 32
typedef __attribute__((ext_vector_type(8))) _Float16 f16x8;
typedef __attribute__((ext_vector_type(4))) float f32x4;
typedef unsigned short ushort_t;

__device__ inline unsigned pack_f16(float a, float b) {
    __half2 h = __floats2half2_rn(a, b);
    return __builtin_bit_cast(unsigned, h);
}
__device__ inline ushort_t f16_of(float f) {
    __half h = __float2half_rn(f);
    return __builtin_bit_cast(ushort_t, h);
}
__device__ inline __half2 hmax2(__half2 a, __half2 b) {
    unsigned ua = __builtin_bit_cast(unsigned, a);
    unsigned ub = __builtin_bit_cast(unsigned, b);
    unsigned r;
    asm("v_pk_max_f16 %0, %1, %2" : "=v"(r) : "v"(ua), "v"(ub));
    return __builtin_bit_cast(__half2, r);
}

struct __align__(16) H8 { __half2 h[4]; };

// ---- prep: weight transpose (blocks 0..3) + zero count / ov_cnt ----
__global__ void prep(const float* __restrict__ W0, const float* __restrict__ W1,
                     const float* __restrict__ W2, const float* __restrict__ W3,
                     ushort_t* __restrict__ Wt4, int* __restrict__ count,
                     int* __restrict__ ov_cnt, int N) {
    __shared__ ushort_t sT[D * D];
    const int t = threadIdx.x;
    if (blockIdx.x < 4) {
        const float* src = blockIdx.x == 0 ? W0 : blockIdx.x == 1 ? W1 : blockIdx.x == 2 ? W2 : W3;
        ushort_t* dst = Wt4 + (size_t)blockIdx.x * (D * D);
        for (int i = t; i < D * D; i += 256) {
            const int k = i >> 7, col = i & 127;
            sT[col * D + k] = f16_of(src[i]);
        }
        __syncthreads();
        const uint4* s8 = (const uint4*)sT;
        uint4* d8 = (uint4*)dst;
        for (int i = t; i < D * D / 8; i += 256) d8[i] = s8[i];
    } else {
        if (blockIdx.x == 4 && t == 0) *ov_cnt = 0;
        for (int i = (blockIdx.x - 4) * 256 + t; i < N; i += (gridDim.x - 4) * 256)
            count[i] = 0;
    }
}

// ---- LDS staging helpers (XOR-swizzled layout, 256B rows) ----
__device__ inline void stage_w(ushort_t* sW, const ushort_t* Wt, int t) {
    const uint4* src = (const uint4*)Wt;
    for (int s = t; s < 2048; s += 256) {
        const int col = s >> 4;
        const int off = (s & 15) * 16;
        *(uint4*)((char*)sW + col * 256 + (off ^ ((col & 7) << 4))) = src[s];
    }
}
__device__ inline void stage_x(ushort_t* sX, const float* X, const int* rowidx,
                               int r0, int M, int t) {
    const int row = t >> 2, q = t & 3;
    const int gr = r0 + row;
    if (gr < M) {
        const int src = rowidx ? rowidx[gr] : gr;
        const float* xp = X + (size_t)src * D + q * 32;
        #pragma unroll
        for (int s = 0; s < 4; ++s) {
            const float4 v0 = *(const float4*)(xp + s * 8);
            const float4 v1 = *(const float4*)(xp + s * 8 + 4);
            uint4 pk;
            pk.x = pack_f16(v0.x, v0.y); pk.y = pack_f16(v0.z, v0.w);
            pk.z = pack_f16(v1.x, v1.y); pk.w = pack_f16(v1.z, v1.w);
            const int off = q * 64 + s * 16;
            *(uint4*)((char*)sX + row * 256 + (off ^ ((row & 7) << 4))) = pk;
        }
    }
}

// dual-weight 64-row tile: Y[gr][0:128]=X@(sWA), Y[gr][128:256]=X@(sWB), fp16 out
__device__ inline void dual_tile(const float* X, int r0, int M, ushort_t* Y,
                                 ushort_t* sWA, ushort_t* sWB, ushort_t* sX, int t) {
    const int wave = t >> 6, lane = t & 63;
    const int l15 = lane & 15, lg = lane >> 4;
    stage_x(sX, X, nullptr, r0, M, t);
    __syncthreads();
    f32x4 accA[8], accB[8];
    #pragma unroll
    for (int ct = 0; ct < 8; ++ct) {
        accA[ct] = (f32x4){0.f, 0.f, 0.f, 0.f};
        accB[ct] = (f32x4){0.f, 0.f, 0.f, 0.f};
    }
    #pragma unroll
    for (int kc = 0; kc < 4; ++kc) {
        const int koff = kc * 64 + lg * 16;
        const int arow = wave * 16 + l15;
        const f16x8 afrag = *(const f16x8*)((char*)sX + arow * 256 + (koff ^ ((arow & 7) << 4)));
        #pragma unroll
        for (int ct = 0; ct < 8; ++ct) {
            const int col = ct * 16 + l15;
            const int sw = koff ^ ((col & 7) << 4);
            const f16x8 bfA = *(const f16x8*)((char*)sWA + col * 256 + sw);
            const f16x8 bfB = *(const f16x8*)((char*)sWB + col * 256 + sw);
            accA[ct] = __builtin_amdgcn_mfma_f32_16x16x32_f16(afrag, bfA, accA[ct], 0, 0, 0);
            accB[ct] = __builtin_amdgcn_mfma_f32_16x16x32_f16(afrag, bfB, accB[ct], 0, 0, 0);
        }
    }
    __syncthreads();   // all LDS reads done before caller restages
    #pragma unroll
    for (int q2 = 0; q2 < 4; ++q2) {
        const int gr2 = r0 + wave * 16 + lg * 4 + q2;
        if (gr2 < M) {
            #pragma unroll
            for (int ct = 0; ct < 8; ++ct) {
                const int col = ct * 16 + l15;
                Y[(size_t)gr2 * 256 + col]       = f16_of(accA[ct][q2]);
                Y[(size_t)gr2 * 256 + 128 + col] = f16_of(accB[ct][q2]);
            }
        }
    }
}

// ---------- fused bucket-scatter || projections (block-role split) ----------
// blocks [0,SC):            read edges, bucket[obj*32+pos] = rec (overflow -> ov list)
// blocks [SC,SC+HB):        combo = [hidden@Wh | hidden@Ws], grid-stride tiles
// blocks [SC+HB,SC+HB+RB):  hrcombo = [rela@Wh | rela@Wr]
// block  SC+HB+RB:          qrb = rela[q_rel]@Wqr + bias
__global__ __launch_bounds__(256, 2)
void scatter_gemm2(const int* __restrict__ edges, int* __restrict__ count,
                   unsigned* __restrict__ bucket, uint2* __restrict__ ov,
                   int* __restrict__ ov_cnt, int E,
                   const float* __restrict__ hidden, const float* __restrict__ rela,
                   const ushort_t* __restrict__ Wt4, const float* __restrict__ bias,
                   const int* __restrict__ q_rel,
                   ushort_t* __restrict__ combo, ushort_t* __restrict__ hrcombo,
                   ushort_t* __restrict__ qrb, int N, int R, int B,
                   int SC, int HB, int TB, int RB) {
    __shared__ ushort_t sWA[D * D];  // 32 KB
    __shared__ ushort_t sWB[D * D];  // 32 KB
    __shared__ ushort_t sX[64 * D];  // 16 KB  (exactly 80 KB -> 2 blocks/CU)
    const int t = threadIdx.x;
    const int bid = blockIdx.x;

    if (bid < SC) {   // ---- bucket scatter role ----
        const uint2* e2 = (const uint2*)edges;
        for (int e = bid * 256 + t; e < E; e += SC * 256) {
            const unsigned r_idx = e2[e * 3 + 0].x;
            const unsigned rel   = e2[e * 3 + 1].x;
            const uint2 so       = e2[e * 3 + 2];     // .x=sub .y=obj
            const unsigned rc = so.x | (rel << 16) | (r_idx << 25);
            const int pos = atomicAdd(&count[so.y], 1);
            if (pos < MAXDEG) bucket[(size_t)so.y * MAXDEG + pos] = rc;
            else { const int i = atomicAdd(ov_cnt, 1); ov[i] = make_uint2(so.y, rc); }
        }
        return;
    }
    const int gid = bid - SC;
    const int wave = t >> 6, lane = t & 63;
    const int l15 = lane & 15, lg = lane >> 4;

    if (gid < HB) {   // ---- combo = [hidden@Wh | hidden@Ws], grid-stride tiles ----
        stage_w(sWA, Wt4 + 3 * D * D, t);       // Wh^T
        stage_w(sWB, Wt4, t);                   // Ws^T
        __syncthreads();
        for (int tile = gid; tile < TB; tile += HB)
            dual_tile(hidden, tile * 64, N, combo, sWA, sWB, sX, t);
    } else if (gid < HB + RB) {   // ---- hrcombo = [rela@Wh | rela@Wr] ----
        stage_w(sWA, Wt4 + 3 * D * D, t);       // Wh^T
        stage_w(sWB, Wt4 + D * D, t);           // Wr^T
        __syncthreads();
        dual_tile(rela, (gid - HB) * 64, R, hrcombo, sWA, sWB, sX, t);
    } else {          // ---- qrb = rela[q_rel]@Wqr + bias ----
        stage_w(sWA, Wt4 + 2 * D * D, t);       // Wqr^T
        __syncthreads();
        stage_x(sX, rela, q_rel, 0, B, t);
        __syncthreads();
        f32x4 acc[8];
        #pragma unroll
        for (int ct = 0; ct < 8; ++ct) acc[ct] = (f32x4){0.f, 0.f, 0.f, 0.f};
        #pragma unroll
        for (int kc = 0; kc < 4; ++kc) {
            const int koff = kc * 64 + lg * 16;
            const int arow = wave * 16 + l15;
            const f16x8 afrag = *(const f16x8*)((char*)sX + arow * 256 + (koff ^ ((arow & 7) << 4)));
            #pragma unroll
            for (int ct = 0; ct < 8; ++ct) {
                const int col = ct * 16 + l15;
                const f16x8 bf = *(const f16x8*)((char*)sWA + col * 256 + (koff ^ ((col & 7) << 4)));
                acc[ct] = __builtin_amdgcn_mfma_f32_16x16x32_f16(afrag, bf, acc[ct], 0, 0, 0);
            }
        }
        #pragma unroll
        for (int q2 = 0; q2 < 4; ++q2) {
            const int gr2 = wave * 16 + lg * 4 + q2;
            if (gr2 < B) {
                #pragma unroll
                for (int ct = 0; ct < 8; ++ct) {
                    const int col = ct * 16 + l15;
                    qrb[(size_t)gr2 * 128 + col] = f16_of(acc[ct][q2] + bias[col]);
                }
            }
        }
    }
}

// ------- per-node aggregation (static node map, fp16): out = relu(sum a*(hw+rw)) -------
__global__ void agg_v11(const unsigned* __restrict__ bucket, const int* __restrict__ count,
                        const uint2* __restrict__ ov, const int* __restrict__ ov_cnt,
                        const __half* __restrict__ combo,    // [N][256]: hw | hs_proj
                        const __half* __restrict__ hrcombo,  // [R][256]: rw | hr_proj
                        const __half* __restrict__ qrb,      // [B][128]: qr_proj
                        const float* __restrict__ Wa,
                        float* __restrict__ out, int N) {
    const int gtid = blockIdx.x * blockDim.x + threadIdx.x;
    const int wave = gtid >> 6;
    const int lane = threadIdx.x & 63;
    const int nwaves = (gridDim.x * blockDim.x) >> 6;
    const int grp = lane >> 4;        // 0..3 : edge slot within wave
    const int sl  = lane & 15;        // 0..15
    const int c   = sl * 8;           // 8 cols per lane
    __half2 wah[4];
    {
        const float4 w0 = *(const float4*)(Wa + c);
        const float4 w1 = *(const float4*)(Wa + c + 4);
        wah[0] = __floats2half2_rn(w0.x, w0.y);
        wah[1] = __floats2half2_rn(w0.z, w0.w);
        wah[2] = __floats2half2_rn(w1.x, w1.y);
        wah[3] = __floats2half2_rn(w1.z, w1.w);
    }
    const __half2 zero2 = __floats2half2_rn(0.f, 0.f);
    for (int n = wave; n < N; n += nwaves) {
        const int deg = count[n];
        const int lim = deg < MAXDEG ? deg : MAXDEG;
        __half2 a0 = zero2, a1 = zero2, a2 = zero2, a3 = zero2;
        for (int e = grp; e < lim; e += 4) {
            const unsigned rc = bucket[(size_t)n * MAXDEG + e];
            const int sub  = rc & 0xFFFF;
            const int rel  = (rc >> 16) & 0x1FF;
            const int ridx = rc >> 25;
            const H8 uhw  = *(const H8*)(combo + (size_t)sub * 256 + c);
            const H8 uhsp = *(const H8*)(combo + (size_t)sub * 256 + 128 + c);
            const H8 urw  = *(const H8*)(hrcombo + (size_t)rel * 256 + c);
            const H8 uhrp = *(const H8*)(hrcombo + (size_t)rel * 256 + 128 + c);
            const H8 uqrp = *(const H8*)(qrb + (size_t)ridx * 128 + c);
            __half2 d2 = zero2;
            #pragma unroll
            for (int j = 0; j < 4; ++j) {
                const __half2 p = hmax2(__hadd2(__hadd2(uhsp.h[j], uhrp.h[j]), uqrp.h[j]), zero2);
                d2 = __hfma2(p, wah[j], d2);
            }
            float part = __low2float(d2) + __high2float(d2);
            #pragma unroll
            for (int off = 8; off > 0; off >>= 1) part += __shfl_xor(part, off, 64);
            const float alpha = 1.f / (1.f + __expf(-part));
            const __half2 al2 = __float2half2_rn(alpha);
            a0 = __hfma2(__hadd2(uhw.h[0], urw.h[0]), al2, a0);
            a1 = __hfma2(__hadd2(uhw.h[1], urw.h[1]), al2, a1);
            a2 = __hfma2(__hadd2(uhw.h[2], urw.h[2]), al2, a2);
            a3 = __hfma2(__hadd2(uhw.h[3], urw.h[3]), al2, a3);
        }
        if (deg > MAXDEG) {   // exact-correctness overflow path (empty in practice)
            const int ovn = *ov_cnt;
            for (int i = grp; i < ovn; i += 4) {
                const uint2 o = ov[i];
                if ((int)o.x != n) continue;
                const unsigned rc = o.y;
                const int sub  = rc & 0xFFFF;
                const int rel  = (rc >> 16) & 0x1FF;
                const int ridx = rc >> 25;
                const H8 uhw  = *(const H8*)(combo + (size_t)sub * 256 + c);
                const H8 uhsp = *(const H8*)(combo + (size_t)sub * 256 + 128 + c);
                const H8 urw  = *(const H8*)(hrcombo + (size_t)rel * 256 + c);
                const H8 uhrp = *(const H8*)(hrcombo + (size_t)rel * 256 + 128 + c);
                const H8 uqrp = *(const H8*)(qrb + (size_t)ridx * 128 + c);
                __half2 d2 = zero2;
                #pragma unroll
                for (int j = 0; j < 4; ++j) {
                    const __half2 p = hmax2(__hadd2(__hadd2(uhsp.h[j], uhrp.h[j]), uqrp.h[j]), zero2);
                    d2 = __hfma2(p, wah[j], d2);
                }
                float part = __low2float(d2) + __high2float(d2);
                #pragma unroll
                for (int off = 8; off > 0; off >>= 1) part += __shfl_xor(part, off, 64);
                const float alpha = 1.f / (1.f + __expf(-part));
                const __half2 al2 = __float2half2_rn(alpha);
                a0 = __hfma2(__hadd2(uhw.h[0], urw.h[0]), al2, a0);
                a1 = __hfma2(__hadd2(uhw.h[1], urw.h[1]), al2, a1);
                a2 = __hfma2(__hadd2(uhw.h[2], urw.h[2]), al2, a2);
                a3 = __hfma2(__hadd2(uhw.h[3], urw.h[3]), al2, a3);
            }
        }
        __half2 aa[4] = {a0, a1, a2, a3};
        #pragma unroll
        for (int j = 0; j < 4; ++j) {   // combine the 4 edge slots
            unsigned u = __builtin_bit_cast(unsigned, aa[j]);
            __half2 s = __hadd2(aa[j], __builtin_bit_cast(__half2, __shfl_xor(u, 16, 64)));
            u = __builtin_bit_cast(unsigned, s);
            aa[j] = __hadd2(s, __builtin_bit_cast(__half2, __shfl_xor(u, 32, 64)));
        }
        if (grp == 0) {
            const float4 o0 = make_float4(fmaxf(__low2float(aa[0]), 0.f), fmaxf(__high2float(aa[0]), 0.f),
                                          fmaxf(__low2float(aa[1]), 0.f), fmaxf(__high2float(aa[1]), 0.f));
            const float4 o1 = make_float4(fmaxf(__low2float(aa[2]), 0.f), fmaxf(__high2float(aa[2]), 0.f),
                                          fmaxf(__low2float(aa[3]), 0.f), fmaxf(__high2float(aa[3]), 0.f));
            *(float4*)(out + (size_t)n * D + c)     = o0;
            *(float4*)(out + (size_t)n * D + c + 4) = o1;
        }
    }
}

extern "C" void kernel_launch(void* const* d_in, const int* in_sizes, int n_in,
                              void* d_out, int out_size, void* d_ws, size_t ws_size,
                              hipStream_t stream) {
    const int*   q_rel  = (const int*)d_in[0];
    const float* hidden = (const float*)d_in[1];
    const int*   edges  = (const int*)d_in[2];
    const float* rela   = (const float*)d_in[3];
    const float* Ws     = (const float*)d_in[4];
    const float* Wr     = (const float*)d_in[5];
    const float* Wqr_w  = (const float*)d_in[6];
    const float* Wqr_b  = (const float*)d_in[7];
    const float* Wa     = (const float*)d_in[8];
    const float* Wh     = (const float*)d_in[9];

    const int B = in_sizes[0];
    const int N = in_sizes[1] / D;
    const int E = in_sizes[2] / 6;
    const int R = in_sizes[3] / D;

    ushort_t* combo   = (ushort_t*)d_ws;                 // N*256 fp16: hw | hs_proj
    ushort_t* hrcombo = combo + (size_t)N * 256;         // R*256 fp16: rw | hr_proj
    ushort_t* qrb     = hrcombo + (size_t)R * 256;       // B*128 fp16
    ushort_t* Wt4     = qrb + (size_t)B * 128;           // 4*128*128 fp16
    int* count  = (int*)(Wt4 + 4 * D * D);               // N
    int* ov_cnt = count + N;                             // 1 (+pad)
    unsigned* bucket = (unsigned*)(ov_cnt + 4);          // N*MAXDEG
    uint2* ov = (uint2*)(((uintptr_t)(bucket + (size_t)N * MAXDEG) + 15) & ~(uintptr_t)15); // E

    // 1) weight transpose + zero counters
    prep<<<200, 256, 0, stream>>>(Ws, Wr, Wqr_w, Wh, Wt4, count, ov_cnt, N);

    // 2) bucket scatter || all projections (grid exactly 512 = full residency)
    //    HB chosen so the hidden tile count divides evenly: TB = 782 = 2*391.
    const int TB = (N + 63) / 64;
    const int RB = (R + 63) / 64;
    int HB = (TB + 1) / 2;                      // 391 for N=50000
    int SC = 512 - HB - RB - 1;                 // 113
    if (SC < 64) { SC = 64; HB = 512 - SC - RB - 1; }
    scatter_gemm2<<<512, 256, 0, stream>>>(
        edges, count, bucket, ov, ov_cnt, E, hidden, rela, Wt4, Wqr_b, q_rel,
        combo, hrcombo, qrb, N, R, B, SC, HB, TB, RB);

    // 3) gather-aggregate + relu -> d_out (static node map)
    agg_v11<<<2048, 256, 0, stream>>>(bucket, count, ov, ov_cnt,
                                      (const __half*)combo, (const __half*)hrcombo,
                                      (const __half*)qrb, Wa, (float*)d_out, N);
}

// Round 23
// 88.371 us; speedup vs baseline: 1.1562x; 1.0084x over previous
//
#include <hip/hip_runtime.h>
#include <hip/hip_fp16.h>
#include <math.h>
#include <stdint.h>

#define D 128
#define MAXDEG 32
typedef __attribute__((ext_vector_type(8))) _Float16 f16x8;
typedef __attribute__((ext_vector_type(4))) float f32x4;
typedef unsigned short ushort_t;

__device__ inline unsigned pack_f16(float a, float b) {
    __half2 h = __floats2half2_rn(a, b);
    return __builtin_bit_cast(unsigned, h);
}
__device__ inline ushort_t f16_of(float f) {
    __half h = __float2half_rn(f);
    return __builtin_bit_cast(ushort_t, h);
}
__device__ inline __half2 hmax2(__half2 a, __half2 b) {
    unsigned ua = __builtin_bit_cast(unsigned, a);
    unsigned ub = __builtin_bit_cast(unsigned, b);
    unsigned r;
    asm("v_pk_max_f16 %0, %1, %2" : "=v"(r) : "v"(ua), "v"(ub));
    return __builtin_bit_cast(__half2, r);
}

struct __align__(16) H8 { __half2 h[4]; };

// ---- LDS staging: transpose+convert f32 W[k][col] -> swizzled fp16 sW[col][k] ----
__device__ inline void stage_w_f32(ushort_t* sW, const float* __restrict__ W, int t) {
    for (int i = t * 4; i < D * D; i += 256 * 4) {
        const int k = i >> 7, col0 = i & 127;
        const float4 v = *(const float4*)(W + i);
        const ushort_t h[4] = {f16_of(v.x), f16_of(v.y), f16_of(v.z), f16_of(v.w)};
        #pragma unroll
        for (int j = 0; j < 4; ++j) {
            const int col = col0 + j;
            *(ushort_t*)((char*)sW + col * 256 + ((k * 2) ^ ((col & 7) << 4))) = h[j];
        }
    }
}
__device__ inline void stage_x(ushort_t* sX, const float* X, const int* rowidx,
                               int r0, int M, int t) {
    const int row = t >> 2, q = t & 3;
    const int gr = r0 + row;
    if (gr < M) {
        const int src = rowidx ? rowidx[gr] : gr;
        const float* xp = X + (size_t)src * D + q * 32;
        #pragma unroll
        for (int s = 0; s < 4; ++s) {
            const float4 v0 = *(const float4*)(xp + s * 8);
            const float4 v1 = *(const float4*)(xp + s * 8 + 4);
            uint4 pk;
            pk.x = pack_f16(v0.x, v0.y); pk.y = pack_f16(v0.z, v0.w);
            pk.z = pack_f16(v1.x, v1.y); pk.w = pack_f16(v1.z, v1.w);
            const int off = q * 64 + s * 16;
            *(uint4*)((char*)sX + row * 256 + (off ^ ((row & 7) << 4))) = pk;
        }
    }
}

// dual-weight 64-row tile: Y[gr][0:128]=X@(sWA), Y[gr][128:256]=X@(sWB), fp16 out
__device__ inline void dual_tile(const float* X, int r0, int M, ushort_t* Y,
                                 ushort_t* sWA, ushort_t* sWB, ushort_t* sX, int t) {
    const int wave = t >> 6, lane = t & 63;
    const int l15 = lane & 15, lg = lane >> 4;
    stage_x(sX, X, nullptr, r0, M, t);
    __syncthreads();
    f32x4 accA[8], accB[8];
    #pragma unroll
    for (int ct = 0; ct < 8; ++ct) {
        accA[ct] = (f32x4){0.f, 0.f, 0.f, 0.f};
        accB[ct] = (f32x4){0.f, 0.f, 0.f, 0.f};
    }
    #pragma unroll
    for (int kc = 0; kc < 4; ++kc) {
        const int koff = kc * 64 + lg * 16;
        const int arow = wave * 16 + l15;
        const f16x8 afrag = *(const f16x8*)((char*)sX + arow * 256 + (koff ^ ((arow & 7) << 4)));
        #pragma unroll
        for (int ct = 0; ct < 8; ++ct) {
            const int col = ct * 16 + l15;
            const int sw = koff ^ ((col & 7) << 4);
            const f16x8 bfA = *(const f16x8*)((char*)sWA + col * 256 + sw);
            const f16x8 bfB = *(const f16x8*)((char*)sWB + col * 256 + sw);
            accA[ct] = __builtin_amdgcn_mfma_f32_16x16x32_f16(afrag, bfA, accA[ct], 0, 0, 0);
            accB[ct] = __builtin_amdgcn_mfma_f32_16x16x32_f16(afrag, bfB, accB[ct], 0, 0, 0);
        }
    }
    __syncthreads();   // all LDS reads done before caller restages
    #pragma unroll
    for (int q2 = 0; q2 < 4; ++q2) {
        const int gr2 = r0 + wave * 16 + lg * 4 + q2;
        if (gr2 < M) {
            #pragma unroll
            for (int ct = 0; ct < 8; ++ct) {
                const int col = ct * 16 + l15;
                Y[(size_t)gr2 * 256 + col]       = f16_of(accA[ct][q2]);
                Y[(size_t)gr2 * 256 + 128 + col] = f16_of(accB[ct][q2]);
            }
        }
    }
}

// ---------- fused bucket-scatter || projections (block-role split) ----------
// blocks [0,SC):            read edges, bucket[obj*32+pos] = rec (overflow -> ov list)
// blocks [SC,SC+HB):        combo = [hidden@Wh | hidden@Ws], grid-stride tiles
// blocks [SC+HB,SC+HB+RB):  hrcombo = [rela@Wh | rela@Wr]
// block  SC+HB+RB:          qrb = rela[q_rel]@Wqr + bias
__global__ __launch_bounds__(256, 2)
void scatter_gemm2(const int* __restrict__ edges, int* __restrict__ count,
                   unsigned* __restrict__ bucket, uint2* __restrict__ ov,
                   int* __restrict__ ov_cnt, int E,
                   const float* __restrict__ hidden, const float* __restrict__ rela,
                   const float* __restrict__ Ws, const float* __restrict__ Wr,
                   const float* __restrict__ Wqr_w, const float* __restrict__ Wh,
                   const float* __restrict__ bias, const int* __restrict__ q_rel,
                   ushort_t* __restrict__ combo, ushort_t* __restrict__ hrcombo,
                   ushort_t* __restrict__ qrb, int N, int R, int B,
                   int SC, int HB, int TB, int RB) {
    __shared__ ushort_t sWA[D * D];  // 32 KB
    __shared__ ushort_t sWB[D * D];  // 32 KB
    __shared__ ushort_t sX[64 * D];  // 16 KB  (exactly 80 KB -> 2 blocks/CU)
    const int t = threadIdx.x;
    const int bid = blockIdx.x;

    if (bid < SC) {   // ---- bucket scatter role ----
        const uint2* e2 = (const uint2*)edges;
        for (int e = bid * 256 + t; e < E; e += SC * 256) {
            const unsigned r_idx = e2[e * 3 + 0].x;
            const unsigned rel   = e2[e * 3 + 1].x;
            const uint2 so       = e2[e * 3 + 2];     // .x=sub .y=obj
            const unsigned rc = so.x | (rel << 16) | (r_idx << 25);
            const int pos = atomicAdd(&count[so.y], 1);
            if (pos < MAXDEG) bucket[(size_t)so.y * MAXDEG + pos] = rc;
            else { const int i = atomicAdd(ov_cnt, 1); ov[i] = make_uint2(so.y, rc); }
        }
        return;
    }
    const int gid = bid - SC;
    const int wave = t >> 6, lane = t & 63;
    const int l15 = lane & 15, lg = lane >> 4;

    if (gid < HB) {   // ---- combo = [hidden@Wh | hidden@Ws], grid-stride tiles ----
        stage_w_f32(sWA, Wh, t);
        stage_w_f32(sWB, Ws, t);
        __syncthreads();
        for (int tile = gid; tile < TB; tile += HB)
            dual_tile(hidden, tile * 64, N, combo, sWA, sWB, sX, t);
    } else if (gid < HB + RB) {   // ---- hrcombo = [rela@Wh | rela@Wr] ----
        stage_w_f32(sWA, Wh, t);
        stage_w_f32(sWB, Wr, t);
        __syncthreads();
        dual_tile(rela, (gid - HB) * 64, R, hrcombo, sWA, sWB, sX, t);
    } else {          // ---- qrb = rela[q_rel]@Wqr + bias ----
        stage_w_f32(sWA, Wqr_w, t);
        __syncthreads();
        stage_x(sX, rela, q_rel, 0, B, t);
        __syncthreads();
        f32x4 acc[8];
        #pragma unroll
        for (int ct = 0; ct < 8; ++ct) acc[ct] = (f32x4){0.f, 0.f, 0.f, 0.f};
        #pragma unroll
        for (int kc = 0; kc < 4; ++kc) {
            const int koff = kc * 64 + lg * 16;
            const int arow = wave * 16 + l15;
            const f16x8 afrag = *(const f16x8*)((char*)sX + arow * 256 + (koff ^ ((arow & 7) << 4)));
            #pragma unroll
            for (int ct = 0; ct < 8; ++ct) {
                const int col = ct * 16 + l15;
                const f16x8 bf = *(const f16x8*)((char*)sWA + col * 256 + (koff ^ ((col & 7) << 4)));
                acc[ct] = __builtin_amdgcn_mfma_f32_16x16x32_f16(afrag, bf, acc[ct], 0, 0, 0);
            }
        }
        #pragma unroll
        for (int q2 = 0; q2 < 4; ++q2) {
            const int gr2 = wave * 16 + lg * 4 + q2;
            if (gr2 < B) {
                #pragma unroll
                for (int ct = 0; ct < 8; ++ct) {
                    const int col = ct * 16 + l15;
                    qrb[(size_t)gr2 * 128 + col] = f16_of(acc[ct][q2] + bias[col]);
                }
            }
        }
    }
}

// ------- per-node aggregation (static node map, fp16): out = relu(sum a*(hw+rw)) -------
__global__ void agg_v11(const unsigned* __restrict__ bucket, const int* __restrict__ count,
                        const uint2* __restrict__ ov, const int* __restrict__ ov_cnt,
                        const __half* __restrict__ combo,    // [N][256]: hw | hs_proj
                        const __half* __restrict__ hrcombo,  // [R][256]: rw | hr_proj
                        const __half* __restrict__ qrb,      // [B][128]: qr_proj
                        const float* __restrict__ Wa,
                        float* __restrict__ out, int N) {
    const int gtid = blockIdx.x * blockDim.x + threadIdx.x;
    const int wave = gtid >> 6;
    const int lane = threadIdx.x & 63;
    const int nwaves = (gridDim.x * blockDim.x) >> 6;
    const int grp = lane >> 4;        // 0..3 : edge slot within wave
    const int sl  = lane & 15;        // 0..15
    const int c   = sl * 8;           // 8 cols per lane
    __half2 wah[4];
    {
        const float4 w0 = *(const float4*)(Wa + c);
        const float4 w1 = *(const float4*)(Wa + c + 4);
        wah[0] = __floats2half2_rn(w0.x, w0.y);
        wah[1] = __floats2half2_rn(w0.z, w0.w);
        wah[2] = __floats2half2_rn(w1.x, w1.y);
        wah[3] = __floats2half2_rn(w1.z, w1.w);
    }
    const __half2 zero2 = __floats2half2_rn(0.f, 0.f);
    for (int n = wave; n < N; n += nwaves) {
        const int deg = count[n];
        const int lim = deg < MAXDEG ? deg : MAXDEG;
        __half2 a0 = zero2, a1 = zero2, a2 = zero2, a3 = zero2;
        for (int e = grp; e < lim; e += 4) {
            const unsigned rc = bucket[(size_t)n * MAXDEG + e];
            const int sub  = rc & 0xFFFF;
            const int rel  = (rc >> 16) & 0x1FF;
            const int ridx = rc >> 25;
            const H8 uhw  = *(const H8*)(combo + (size_t)sub * 256 + c);
            const H8 uhsp = *(const H8*)(combo + (size_t)sub * 256 + 128 + c);
            const H8 urw  = *(const H8*)(hrcombo + (size_t)rel * 256 + c);
            const H8 uhrp = *(const H8*)(hrcombo + (size_t)rel * 256 + 128 + c);
            const H8 uqrp = *(const H8*)(qrb + (size_t)ridx * 128 + c);
            __half2 d2 = zero2;
            #pragma unroll
            for (int j = 0; j < 4; ++j) {
                const __half2 p = hmax2(__hadd2(__hadd2(uhsp.h[j], uhrp.h[j]), uqrp.h[j]), zero2);
                d2 = __hfma2(p, wah[j], d2);
            }
            float part = __low2float(d2) + __high2float(d2);
            #pragma unroll
            for (int off = 8; off > 0; off >>= 1) part += __shfl_xor(part, off, 64);
            const float alpha = 1.f / (1.f + __expf(-part));
            const __half2 al2 = __float2half2_rn(alpha);
            a0 = __hfma2(__hadd2(uhw.h[0], urw.h[0]), al2, a0);
            a1 = __hfma2(__hadd2(uhw.h[1], urw.h[1]), al2, a1);
            a2 = __hfma2(__hadd2(uhw.h[2], urw.h[2]), al2, a2);
            a3 = __hfma2(__hadd2(uhw.h[3], urw.h[3]), al2, a3);
        }
        if (deg > MAXDEG) {   // exact-correctness overflow path (empty in practice)
            const int ovn = *ov_cnt;
            for (int i = grp; i < ovn; i += 4) {
                const uint2 o = ov[i];
                if ((int)o.x != n) continue;
                const unsigned rc = o.y;
                const int sub  = rc & 0xFFFF;
                const int rel  = (rc >> 16) & 0x1FF;
                const int ridx = rc >> 25;
                const H8 uhw  = *(const H8*)(combo + (size_t)sub * 256 + c);
                const H8 uhsp = *(const H8*)(combo + (size_t)sub * 256 + 128 + c);
                const H8 urw  = *(const H8*)(hrcombo + (size_t)rel * 256 + c);
                const H8 uhrp = *(const H8*)(hrcombo + (size_t)rel * 256 + 128 + c);
                const H8 uqrp = *(const H8*)(qrb + (size_t)ridx * 128 + c);
                __half2 d2 = zero2;
                #pragma unroll
                for (int j = 0; j < 4; ++j) {
                    const __half2 p = hmax2(__hadd2(__hadd2(uhsp.h[j], uhrp.h[j]), uqrp.h[j]), zero2);
                    d2 = __hfma2(p, wah[j], d2);
                }
                float part = __low2float(d2) + __high2float(d2);
                #pragma unroll
                for (int off = 8; off > 0; off >>= 1) part += __shfl_xor(part, off, 64);
                const float alpha = 1.f / (1.f + __expf(-part));
                const __half2 al2 = __float2half2_rn(alpha);
                a0 = __hfma2(__hadd2(uhw.h[0], urw.h[0]), al2, a0);
                a1 = __hfma2(__hadd2(uhw.h[1], urw.h[1]), al2, a1);
                a2 = __hfma2(__hadd2(uhw.h[2], urw.h[2]), al2, a2);
                a3 = __hfma2(__hadd2(uhw.h[3], urw.h[3]), al2, a3);
            }
        }
        __half2 aa[4] = {a0, a1, a2, a3};
        #pragma unroll
        for (int j = 0; j < 4; ++j) {   // combine the 4 edge slots
            unsigned u = __builtin_bit_cast(unsigned, aa[j]);
            __half2 s = __hadd2(aa[j], __builtin_bit_cast(__half2, __shfl_xor(u, 16, 64)));
            u = __builtin_bit_cast(unsigned, s);
            aa[j] = __hadd2(s, __builtin_bit_cast(__half2, __shfl_xor(u, 32, 64)));
        }
        if (grp == 0) {
            const float4 o0 = make_float4(fmaxf(__low2float(aa[0]), 0.f), fmaxf(__high2float(aa[0]), 0.f),
                                          fmaxf(__low2float(aa[1]), 0.f), fmaxf(__high2float(aa[1]), 0.f));
            const float4 o1 = make_float4(fmaxf(__low2float(aa[2]), 0.f), fmaxf(__high2float(aa[2]), 0.f),
                                          fmaxf(__low2float(aa[3]), 0.f), fmaxf(__high2float(aa[3]), 0.f));
            *(float4*)(out + (size_t)n * D + c)     = o0;
            *(float4*)(out + (size_t)n * D + c + 4) = o1;
        }
    }
}

extern "C" void kernel_launch(void* const* d_in, const int* in_sizes, int n_in,
                              void* d_out, int out_size, void* d_ws, size_t ws_size,
                              hipStream_t stream) {
    const int*   q_rel  = (const int*)d_in[0];
    const float* hidden = (const float*)d_in[1];
    const int*   edges  = (const int*)d_in[2];
    const float* rela   = (const float*)d_in[3];
    const float* Ws     = (const float*)d_in[4];
    const float* Wr     = (const float*)d_in[5];
    const float* Wqr_w  = (const float*)d_in[6];
    const float* Wqr_b  = (const float*)d_in[7];
    const float* Wa     = (const float*)d_in[8];
    const float* Wh     = (const float*)d_in[9];

    const int B = in_sizes[0];
    const int N = in_sizes[1] / D;
    const int E = in_sizes[2] / 6;
    const int R = in_sizes[3] / D;

    ushort_t* combo   = (ushort_t*)d_ws;                 // N*256 fp16: hw | hs_proj
    ushort_t* hrcombo = combo + (size_t)N * 256;         // R*256 fp16: rw | hr_proj
    ushort_t* qrb     = hrcombo + (size_t)R * 256;       // B*128 fp16
    int* count  = (int*)(qrb + (size_t)B * 128);         // N
    int* ov_cnt = count + N;                             // 1 (+pad)
    unsigned* bucket = (unsigned*)(ov_cnt + 4);          // N*MAXDEG
    uint2* ov = (uint2*)(((uintptr_t)(bucket + (size_t)N * MAXDEG) + 15) & ~(uintptr_t)15); // E

    // 1) zero counters (count + ov_cnt contiguous)
    (void)hipMemsetAsync(count, 0, ((size_t)N + 4) * sizeof(int), stream);

    // 2) bucket scatter || all projections (in-block weight transpose, grid = 512)
    const int TB = (N + 63) / 64;
    const int RB = (R + 63) / 64;
    int HB = (TB + 1) / 2;                      // 391 for N=50000 (2 tiles/block, even)
    int SC = 512 - HB - RB - 1;                 // 113
    if (SC < 64) { SC = 64; HB = 512 - SC - RB - 1; }
    scatter_gemm2<<<512, 256, 0, stream>>>(
        edges, count, bucket, ov, ov_cnt, E, hidden, rela,
        Ws, Wr, Wqr_w, Wh, Wqr_b, q_rel,
        combo, hrcombo, qrb, N, R, B, SC, HB, TB, RB);

    // 3) gather-aggregate + relu -> d_out (static node map)
    agg_v11<<<2048, 256, 0, stream>>>(bucket, count, ov, ov_cnt,
                                      (const __half*)combo, (const __half*)hrcombo,
                                      (const __half*)qrb, Wa, (float*)d_out, N);
}